// Round 3
// baseline (820.036 us; speedup 1.0000x reference)
//
#include <hip/hip_runtime.h>
#include <math.h>

// Problem constants (from reference): B=8192 tokens, N=4096 neurons, K=4.
constexpr int B = 8192;
constexpr int N = 4096;
constexpr int K = 4;

constexpr int NBLK = 256;   // threads per block
constexpr int NPT  = 4;     // consecutive neurons per thread (float4 lane)
constexpr int BPT  = 4;     // batch rows per thread (W reuse + ILP)
constexpr int NT   = N / (NBLK * NPT);   // 4 n-tiles
constexpr int BT   = B / BPT;            // 2048 b-tiles
static_assert(NT == 4, "block-index decode assumes 4 n-tiles");

typedef float f32x4 __attribute__((ext_vector_type(4)));

__device__ __forceinline__ float fast_rcp(float x) {
    return __builtin_amdgcn_rcpf(x);   // v_rcp_f32, ~1 ulp
}

// s: [B,N] f32   W: [N,K,K] f32 (L2-resident)   bias: [N,K] f32
// out: res [B,N] then alpha [B,N,K], concatenated f32.
__global__ __launch_bounds__(256) void mix_kernel(
    const float* __restrict__ s,
    const float* __restrict__ W,
    const float* __restrict__ bias,
    float* __restrict__ res,
    float* __restrict__ alpha)
{
    const int tid = threadIdx.x;
    const int nt  = blockIdx.x & (NT - 1);
    const int bt  = blockIdx.x >> 2;          // NT == 4
    const int n0  = nt * (NBLK * NPT) + tid * NPT;
    const int b0  = bt * BPT;

    // Streaming s rows: 4x float4 nontemporal loads (no reuse).
    f32x4 sv[BPT];
#pragma unroll
    for (int j = 0; j < BPT; ++j)
        sv[j] = __builtin_nontemporal_load(
            (const f32x4*)(s + (size_t)(b0 + j) * N + n0));

    // Per-neuron weights for this thread's 4 neurons (cached, L2-hit).
    f32x4 w[NPT][K];
    f32x4 bb[NPT];
#pragma unroll
    for (int i = 0; i < NPT; ++i) {
        const f32x4* Wp = (const f32x4*)(W + (size_t)(n0 + i) * (K * K));
#pragma unroll
        for (int k = 0; k < K; ++k) w[i][k] = Wp[k];
        bb[i] = ((const f32x4*)bias)[n0 + i];
    }

#pragma unroll
    for (int j = 0; j < BPT; ++j) {
        const size_t row = (size_t)(b0 + j) * N + n0;   // float index of elem i=0
        f32x4 rout;
#pragma unroll
        for (int i = 0; i < NPT; ++i) {
            const float x  = sv[j][i];

            // Activations via a single exp: e = exp(-|x|).
            const float ax = fabsf(x);
            const float e  = __expf(-ax);
            const float e2 = e * e;
            const float a0 = fmaxf(x, 0.0f);                      // relu
            const float a1 = (x >= 0.0f ? 1.0f : e) * fast_rcp(1.0f + e);  // sigmoid
            const float t  = (1.0f - e2) * fast_rcp(1.0f + e2);
            const float a2 = copysignf(t, x);                     // tanh
            const float a3 = x;                                   // identity

            const f32x4 w0 = w[i][0], w1 = w[i][1], w2 = w[i][2], w3 = w[i][3];
            const float l0 = fmaf(a0, w0[0], fmaf(a1, w1[0], fmaf(a2, w2[0], fmaf(a3, w3[0], bb[i][0]))));
            const float l1 = fmaf(a0, w0[1], fmaf(a1, w1[1], fmaf(a2, w2[1], fmaf(a3, w3[1], bb[i][1]))));
            const float l2 = fmaf(a0, w0[2], fmaf(a1, w1[2], fmaf(a2, w2[2], fmaf(a3, w3[2], bb[i][2]))));
            const float l3 = fmaf(a0, w0[3], fmaf(a1, w1[3], fmaf(a2, w2[3], fmaf(a3, w3[3], bb[i][3]))));

            // softmax over 4 logits; |logits| small enough that exp can't
            // overflow f32, so skip max-subtraction.
            const float e0 = __expf(l0);
            const float e1 = __expf(l1);
            const float e2v = __expf(l2);
            const float e3 = __expf(l3);
            const float inv = fast_rcp(e0 + e1 + e2v + e3);
            const float p0 = e0 * inv, p1 = e1 * inv, p2 = e2v * inv, p3 = e3 * inv;

            f32x4 pv; pv[0] = p0; pv[1] = p1; pv[2] = p2; pv[3] = p3;
            __builtin_nontemporal_store(pv, (f32x4*)alpha + row + i);

            rout[i] = fmaf(p0, a0, fmaf(p1, a1, fmaf(p2, a2, p3 * a3)));
        }
        __builtin_nontemporal_store(rout, (f32x4*)(res + row));
    }
}

extern "C" void kernel_launch(void* const* d_in, const int* in_sizes, int n_in,
                              void* d_out, int out_size, void* d_ws, size_t ws_size,
                              hipStream_t stream) {
    const float* s    = (const float*)d_in[0];   // [B, N]
    const float* W    = (const float*)d_in[1];   // [N, K, K]
    const float* bias = (const float*)d_in[2];   // [N, K]

    float* res   = (float*)d_out;                      // [B, N]
    float* alpha = (float*)d_out + (size_t)B * N;      // [B, N, K]

    const int grid = NT * BT;   // 4 * 2048 = 8192 blocks
    mix_kernel<<<grid, NBLK, 0, stream>>>(s, W, bias, res, alpha);
}

// Round 4
// 193.478 us; speedup vs baseline: 4.2384x; 4.2384x over previous
//
#include <hip/hip_runtime.h>
#include <math.h>

// Problem constants (from reference): B=8192 tokens, N=4096 neurons, K=4.
constexpr int B = 8192;
constexpr int N = 4096;
constexpr int K = 4;

constexpr int NBLK   = 256;          // threads per block = 256 consecutive n
constexpr int BPT    = 8;            // b-rows per thread (W reuse + ILP + store MLP)
constexpr int NTILES = N / NBLK;     // 16 n-tiles per b-row
constexpr int BT     = B / BPT;      // 1024 b-tiles

typedef float f32x4 __attribute__((ext_vector_type(4)));

__device__ __forceinline__ float fast_rcp(float x) {
    return __builtin_amdgcn_rcpf(x);   // v_rcp_f32, ~1 ulp — fine vs 0.1 threshold
}

// s: [B,N] f32   W: [N,K,K] f32 (256 KB, L2/L3-resident)   bias: [N,K] f32
// out: res [B,N] then alpha [B,N,K], concatenated f32.
// Mapping: thread <-> one n; BPT consecutive b-rows per thread. Every global
// access is per-instruction lane-contiguous: s load 4 B/lane, res store
// 4 B/lane, alpha store 16 B/lane (1 KB per wave instruction).
__global__ __launch_bounds__(256) void mix_kernel(
    const float* __restrict__ s,
    const float* __restrict__ W,
    const float* __restrict__ bias,
    float* __restrict__ res,
    float* __restrict__ alpha)
{
    const int tid = threadIdx.x;
    const int nt  = blockIdx.x & (NTILES - 1);   // n-tile
    const int bt  = blockIdx.x >> 4;             // b-tile (NTILES == 16)

    const int n  = nt * NBLK + tid;
    const int b0 = bt * BPT;

    // Hoist all s loads: 8 independent coalesced dword loads in flight.
    float sv[BPT];
#pragma unroll
    for (int j = 0; j < BPT; ++j)
        sv[j] = s[(size_t)(b0 + j) * N + n];

    // Per-neuron weights (L2/L3-hit after first touch), reused across 8 rows.
    const f32x4* Wp = (const f32x4*)(W + (size_t)n * (K * K));
    const f32x4 w0 = Wp[0];
    const f32x4 w1 = Wp[1];
    const f32x4 w2 = Wp[2];
    const f32x4 w3 = Wp[3];
    const f32x4 bb = ((const f32x4*)bias)[n];

#pragma unroll
    for (int j = 0; j < BPT; ++j) {
        const size_t idx = (size_t)(b0 + j) * N + n;
        const float x = sv[j];

        // Activations via a single exp: e = exp(-|x|).
        const float ax = fabsf(x);
        const float e  = __expf(-ax);
        const float e2 = e * e;
        const float a0 = fmaxf(x, 0.0f);                               // relu
        const float a1 = (x >= 0.0f ? 1.0f : e) * fast_rcp(1.0f + e);  // sigmoid
        const float t  = (1.0f - e2) * fast_rcp(1.0f + e2);
        const float a2 = copysignf(t, x);                              // tanh
        const float a3 = x;                                            // identity

        // logits[l] = sum_k a_k * W[n,k,l] + b[n,l]
        const float l0 = fmaf(a0, w0[0], fmaf(a1, w1[0], fmaf(a2, w2[0], fmaf(a3, w3[0], bb[0]))));
        const float l1 = fmaf(a0, w0[1], fmaf(a1, w1[1], fmaf(a2, w2[1], fmaf(a3, w3[1], bb[1]))));
        const float l2 = fmaf(a0, w0[2], fmaf(a1, w1[2], fmaf(a2, w2[2], fmaf(a3, w3[2], bb[2]))));
        const float l3 = fmaf(a0, w0[3], fmaf(a1, w1[3], fmaf(a2, w2[3], fmaf(a3, w3[3], bb[3]))));

        // softmax over 4 logits; |logits| is small enough that f32 exp
        // cannot overflow — skip max-subtraction.
        const float e0 = __expf(l0);
        const float e1 = __expf(l1);
        const float e2v = __expf(l2);
        const float e3 = __expf(l3);
        const float inv = fast_rcp(e0 + e1 + e2v + e3);
        const float p0 = e0 * inv, p1 = e1 * inv, p2 = e2v * inv, p3 = e3 * inv;

        f32x4 pv; pv[0] = p0; pv[1] = p1; pv[2] = p2; pv[3] = p3;
        ((f32x4*)alpha)[idx] = pv;                                   // 16 B/lane, contiguous
        res[idx] = fmaf(p0, a0, fmaf(p1, a1, fmaf(p2, a2, p3 * a3))); // 4 B/lane, contiguous
    }
}

extern "C" void kernel_launch(void* const* d_in, const int* in_sizes, int n_in,
                              void* d_out, int out_size, void* d_ws, size_t ws_size,
                              hipStream_t stream) {
    const float* s    = (const float*)d_in[0];   // [B, N]
    const float* W    = (const float*)d_in[1];   // [N, K, K]
    const float* bias = (const float*)d_in[2];   // [N, K]

    float* res   = (float*)d_out;                      // [B, N]
    float* alpha = (float*)d_out + (size_t)B * N;      // [B, N, K]

    const int grid = NTILES * BT;   // 16 * 1024 = 16384 blocks, exact cover
    mix_kernel<<<grid, NBLK, 0, stream>>>(s, W, bias, res, alpha);
}

// Round 5
// 117.145 us; speedup vs baseline: 7.0002x; 1.6516x over previous
//
#include <hip/hip_runtime.h>
#include <math.h>

// Problem constants (from reference): B=8192 tokens, N=4096 neurons, K=4.
constexpr int B = 8192;
constexpr int N = 4096;
constexpr int K = 4;

constexpr int NBLK   = 256;          // threads per block = 256 consecutive n
constexpr int BPT    = 8;            // b-rows per block-thread (W reuse + ILP)
constexpr int NTILES = N / NBLK;     // 16 n-tiles per b-row
constexpr int BT     = B / BPT;      // 1024 b-tiles

typedef float f32x4 __attribute__((ext_vector_type(4)));

__device__ __forceinline__ float fast_rcp(float x) {
    return __builtin_amdgcn_rcpf(x);   // v_rcp_f32, ~1 ulp — fine vs 0.1 threshold
}

// s: [B,N] f32   W: [N,K,K] f32 (256 KB, L2/L3-resident)   bias: [N,K] f32
// out: res [B,N] then alpha [B,N,K], concatenated f32.
//
// Mapping: thread <-> one n, 8 consecutive b-rows. alpha stored directly as
// nontemporal dwordx4 (each wave-store = 1024 contiguous bytes, 4KB-aligned
// base -> full lines, no RMW). res staged in LDS and drained at the end as
// nontemporal dwordx4 wave-stores (1024 contiguous bytes, 1KB-aligned).
__global__ __launch_bounds__(256) void mix_kernel(
    const float* __restrict__ s,
    const float* __restrict__ W,
    const float* __restrict__ bias,
    float* __restrict__ res,
    float* __restrict__ alpha)
{
    __shared__ float res_lds[BPT][NBLK];   // 8 KB

    const int tid = threadIdx.x;
    const int nt  = blockIdx.x & (NTILES - 1);   // n-tile
    const int bt  = blockIdx.x >> 4;             // b-tile (NTILES == 16)

    const int n  = nt * NBLK + tid;
    const int b0 = bt * BPT;

    // Hoist all s loads: 8 independent coalesced dword loads in flight.
    float sv[BPT];
#pragma unroll
    for (int j = 0; j < BPT; ++j)
        sv[j] = s[(size_t)(b0 + j) * N + n];

    // Per-neuron weights (L2/L3-hit after first touch), reused across 8 rows.
    const f32x4* Wp = (const f32x4*)(W + (size_t)n * (K * K));
    const f32x4 w0 = Wp[0];
    const f32x4 w1 = Wp[1];
    const f32x4 w2 = Wp[2];
    const f32x4 w3 = Wp[3];
    const f32x4 bb = ((const f32x4*)bias)[n];

#pragma unroll
    for (int j = 0; j < BPT; ++j) {
        const size_t idx = (size_t)(b0 + j) * N + n;
        const float x = sv[j];

        // Activations via a single exp: e = exp(-|x|).
        const float ax = fabsf(x);
        const float e  = __expf(-ax);
        const float e2 = e * e;
        const float a0 = fmaxf(x, 0.0f);                               // relu
        const float a1 = (x >= 0.0f ? 1.0f : e) * fast_rcp(1.0f + e);  // sigmoid
        const float t  = (1.0f - e2) * fast_rcp(1.0f + e2);
        const float a2 = copysignf(t, x);                              // tanh
        const float a3 = x;                                            // identity

        // logits[l] = sum_k a_k * W[n,k,l] + b[n,l]
        const float l0 = fmaf(a0, w0[0], fmaf(a1, w1[0], fmaf(a2, w2[0], fmaf(a3, w3[0], bb[0]))));
        const float l1 = fmaf(a0, w0[1], fmaf(a1, w1[1], fmaf(a2, w2[1], fmaf(a3, w3[1], bb[1]))));
        const float l2 = fmaf(a0, w0[2], fmaf(a1, w1[2], fmaf(a2, w2[2], fmaf(a3, w3[2], bb[2]))));
        const float l3 = fmaf(a0, w0[3], fmaf(a1, w1[3], fmaf(a2, w2[3], fmaf(a3, w3[3], bb[3]))));

        // softmax over 4 logits; |logits| small enough that f32 exp cannot
        // overflow — skip max-subtraction.
        const float e0 = __expf(l0);
        const float e1 = __expf(l1);
        const float e2v = __expf(l2);
        const float e3 = __expf(l3);
        const float inv = fast_rcp(e0 + e1 + e2v + e3);
        const float p0 = e0 * inv, p1 = e1 * inv, p2 = e2v * inv, p3 = e3 * inv;

        f32x4 pv; pv[0] = p0; pv[1] = p1; pv[2] = p2; pv[3] = p3;
        __builtin_nontemporal_store(pv, (f32x4*)alpha + idx);   // 1024 B/wave, full lines

        res_lds[j][tid] = fmaf(p0, a0, fmaf(p1, a1, fmaf(p2, a2, p3 * a3)));
    }

    __syncthreads();

    // Drain res: 512 float4 per block; thread t handles float4 f = t and t+256.
    // Wave-store = 64 lanes x 16 B = 1024 contiguous bytes (one row-quarter),
    // 1 KB-aligned -> 8 full 128-B lines per instruction.
#pragma unroll
    for (int r = 0; r < 2; ++r) {
        const int f   = r * NBLK + tid;   // float4 index within block tile
        const int row = f >> 6;           // 64 float4 per row
        const int c4  = f & 63;
        f32x4 v;
        v[0] = res_lds[row][c4 * 4 + 0];
        v[1] = res_lds[row][c4 * 4 + 1];
        v[2] = res_lds[row][c4 * 4 + 2];
        v[3] = res_lds[row][c4 * 4 + 3];
        float* dst = res + (size_t)(b0 + row) * N + nt * NBLK + c4 * 4;
        __builtin_nontemporal_store(v, (f32x4*)dst);
    }
}

extern "C" void kernel_launch(void* const* d_in, const int* in_sizes, int n_in,
                              void* d_out, int out_size, void* d_ws, size_t ws_size,
                              hipStream_t stream) {
    const float* s    = (const float*)d_in[0];   // [B, N]
    const float* W    = (const float*)d_in[1];   // [N, K, K]
    const float* bias = (const float*)d_in[2];   // [N, K]

    float* res   = (float*)d_out;                      // [B, N]
    float* alpha = (float*)d_out + (size_t)B * N;      // [B, N, K]

    const int grid = NTILES * BT;   // 16 * 1024 = 16384 blocks, exact cover
    mix_kernel<<<grid, NBLK, 0, stream>>>(s, W, bias, res, alpha);
}